// Round 10
// baseline (490.105 us; speedup 1.0000x reference)
//
#include <hip/hip_runtime.h>
#include <hip/hip_bf16.h>

#define CCH 512
#define TTT 1024
#define BBB 8
#define NGRP 32
#define CPG 16
#define NHEAD 8
#define CHD 64
#define O_QKV 1536

typedef __attribute__((ext_vector_type(8))) short bf16x8;
typedef __attribute__((ext_vector_type(4))) short s16x4;
typedef __attribute__((ext_vector_type(4))) float f32x4;

__device__ __forceinline__ float us2f(unsigned short u) {
  union { unsigned int i; float f; } p; p.i = ((unsigned int)u) << 16; return p.f;
}
__device__ __forceinline__ unsigned short f2us(float f) {
  __hip_bfloat16 b = __float2bfloat16(f);
  return *reinterpret_cast<unsigned short*>(&b);
}
__device__ __forceinline__ bf16x8 cat8(s16x4 a, s16x4 b) {
  bf16x8 r;
  r[0] = a[0]; r[1] = a[1]; r[2] = a[2]; r[3] = a[3];
  r[4] = b[0]; r[5] = b[1]; r[6] = b[2]; r[7] = b[3];
  return r;
}
__device__ __forceinline__ float hmax4(f32x4 v) {
  return fmaxf(fmaxf(v[0], v[1]), fmaxf(v[2], v[3]));
}
__device__ __forceinline__ unsigned int pk2(float lo, float hi) {
  return ((unsigned int)f2us(hi) << 16) | (unsigned int)f2us(lo);
}

// Packed layout for a logical [R rows][K cols] bf16 matrix consumed as MFMA frags:
//   subtile (rt=row/16, kt=k/16) base = (rt*(K/16)+kt)*256
//   within: ((k%16)/4)*64 + (row%16)*4 + (k%4)

// ---------------- W f32 -> packed bf16 (qkv_w then proj_w, one launch) ----------------
__global__ __launch_bounds__(256) void wpack_kernel(
    const float* __restrict__ wq, const float* __restrict__ wp,
    unsigned short* __restrict__ op, int nslot)
{
  const int s = blockIdx.x * 256 + threadIdx.x;   // one ushort4 slot
  if (s >= nslot) return;
  const int u = s & 63, sub = s >> 6;
  const int kt = sub & 31, rt = sub >> 5;         // K = 512 -> 32 kt
  const int lg = u >> 4, lr = u & 15;
  const int row = rt * 16 + lr;
  const float* src = (row < O_QKV) ? &wq[(size_t)row * CCH]
                                   : &wp[(size_t)(row - O_QKV) * CCH];
  float4 v = *reinterpret_cast<const float4*>(&src[kt * 16 + lg * 4]);
  ushort4 r;
  r.x = f2us(v.x); r.y = f2us(v.y); r.z = f2us(v.z); r.w = f2us(v.w);
  reinterpret_cast<ushort4*>(op)[s] = r;
}

// ---------------- GroupNorm: f32 [b][c][t] -> packed H (row=t, k=c) ----------------
__global__ __launch_bounds__(256) void gn_kernel(
    const float* __restrict__ x,
    const float* __restrict__ gw,
    const float* __restrict__ gb,
    unsigned short* __restrict__ hP)
{
  __shared__ __align__(16) float xs[16][1028];
  const int bg = blockIdx.x;
  const int bb = bg >> 5, g = bg & 31;
  const size_t base = ((size_t)bb * CCH + (size_t)g * CPG) * TTT;
  const float4* xv = reinterpret_cast<const float4*>(x + base);
  const int tid = threadIdx.x;

  float s = 0.f, q = 0.f;
  for (int i = tid; i < 4096; i += 256) {
    float4 u = xv[i];
    const int c = i >> 8, t4 = (i & 255) << 2;
    *reinterpret_cast<float4*>(&xs[c][t4]) = u;
    s += (u.x + u.y) + (u.z + u.w);
    q += u.x * u.x + u.y * u.y + u.z * u.z + u.w * u.w;
  }
  #pragma unroll
  for (int off = 32; off > 0; off >>= 1) {
    s += __shfl_down(s, off);
    q += __shfl_down(q, off);
  }
  __shared__ float red[10];
  const int wid = tid >> 6, lane = tid & 63;
  if (lane == 0) { red[wid] = s; red[4 + wid] = q; }
  __syncthreads();
  if (tid == 0) {
    float S = red[0] + red[1] + red[2] + red[3];
    float Q = red[4] + red[5] + red[6] + red[7];
    float mu = S * (1.f / 16384.f);
    float var = Q * (1.f / 16384.f) - mu * mu;
    red[8] = mu;
    red[9] = rsqrtf(var + 1e-5f);
  }
  __syncthreads();
  const float mu = red[8], rstd = red[9];
  float wsc[16], wbs[16];
  #pragma unroll
  for (int cc = 0; cc < 16; cc++) {
    wsc[cc] = gw[g * CPG + cc] * rstd;
    wbs[cc] = gb[g * CPG + cc] - mu * wsc[cc];
  }
  for (int tt = tid; tt < 1024; tt += 256) {
    float v[16];
    #pragma unroll
    for (int cc = 0; cc < 16; cc++)
      v[cc] = fmaf(xs[cc][tt], wsc[cc], wbs[cc]);
    unsigned short* dst = &hP[(size_t)bb * 524288 + ((size_t)((tt >> 4) * 32 + g)) * 256 + (tt & 15) * 4];
    #pragma unroll
    for (int l2 = 0; l2 < 4; l2++) {
      ushort4 st;
      st.x = f2us(v[l2 * 4 + 0]);
      st.y = f2us(v[l2 * 4 + 1]);
      st.z = f2us(v[l2 * 4 + 2]);
      st.w = f2us(v[l2 * 4 + 3]);
      *reinterpret_cast<ushort4*>(&dst[l2 * 64]) = st;
    }
  }
}

// ---------------- LDS-free packed MFMA GEMM (unchanged) ----------------
template<int MODE>
__global__ __launch_bounds__(256) void gemm_p(
    const unsigned short* __restrict__ Ap,
    const unsigned short* __restrict__ Bp,
    const float* __restrict__ bias,
    const float* __restrict__ resid,
    unsigned short* __restrict__ oq,
    unsigned short* __restrict__ ok,
    unsigned short* __restrict__ ov,
    float* __restrict__ of,
    const int O)
{
  const int tid = threadIdx.x;
  const int bz = blockIdx.z, o0 = blockIdx.y << 7, t0 = blockIdx.x << 7;
  const int lane = tid & 63, w = tid >> 6;
  const int lg = lane >> 4, lr = lane & 15;
  const int wr = w >> 1, wc = w & 1;
  const int laneoff = (lg >> 1) * 256 + (lg & 1) * 128 + lr * 4;

  const unsigned short* Ab = Ap + (size_t)(((o0 >> 4) + wr * 4) * 32) * 256 + laneoff;
  const unsigned short* Bb = Bp + (size_t)bz * 524288
      + (size_t)(((t0 >> 4) + wc * 4) * 32) * 256 + laneoff;

  f32x4 acc[4][4];
  #pragma unroll
  for (int m = 0; m < 4; m++)
    #pragma unroll
    for (int n = 0; n < 4; n++) acc[m][n] = f32x4{0.f, 0.f, 0.f, 0.f};

  #pragma unroll 2
  for (int kb = 0; kb < 32; kb += 2) {
    bf16x8 af[4], bf[4];
    #pragma unroll
    for (int m = 0; m < 4; m++) {
      const unsigned short* p = Ab + (m * 32 + kb) * 256;
      af[m] = cat8(*reinterpret_cast<const s16x4*>(p),
                   *reinterpret_cast<const s16x4*>(p + 64));
    }
    #pragma unroll
    for (int n = 0; n < 4; n++) {
      const unsigned short* p = Bb + (n * 32 + kb) * 256;
      bf[n] = cat8(*reinterpret_cast<const s16x4*>(p),
                   *reinterpret_cast<const s16x4*>(p + 64));
    }
    #pragma unroll
    for (int n = 0; n < 4; n++)
      #pragma unroll
      for (int m = 0; m < 4; m++)
        acc[m][n] = __builtin_amdgcn_mfma_f32_16x16x32_bf16(af[m], bf[n], acc[m][n], 0, 0, 0);
  }

  if (MODE == 0) {
    const int a = (o0 >> 6) + wr;
    float bi[4][4];
    #pragma unroll
    for (int m = 0; m < 4; m++)
      #pragma unroll
      for (int r = 0; r < 4; r++)
        bi[m][r] = bias[a * 64 + m * 16 + lg * 4 + r];
    const int head = a / 3, part = a - head * 3;
    const size_t bho = ((size_t)bz * NHEAD + head) << 16;
    if (part < 2) {
      unsigned short* dst = (part == 0 ? oq : ok) + bho;
      #pragma unroll
      for (int n = 0; n < 4; n++) {
        const int rt4 = ((t0 >> 4) + wc * 4 + n) * 4;
        #pragma unroll
        for (int m = 0; m < 4; m++) {
          ushort4 st;
          st.x = f2us(acc[m][n][0] + bi[m][0]);
          st.y = f2us(acc[m][n][1] + bi[m][1]);
          st.z = f2us(acc[m][n][2] + bi[m][2]);
          st.w = f2us(acc[m][n][3] + bi[m][3]);
          *reinterpret_cast<ushort4*>(&dst[((size_t)(rt4 + m) << 8) + lg * 64 + lr * 4]) = st;
        }
      }
    } else {
      unsigned short* dst = ov + bho;
      const int vsub = (lr >> 2) * 64 + (lr & 3);
      #pragma unroll
      for (int m = 0; m < 4; m++)
        #pragma unroll
        for (int n = 0; n < 4; n++) {
          const int kt = (t0 >> 4) + wc * 4 + n;
          unsigned short* q = &dst[((size_t)(m * 64 + kt) << 8) + vsub];
          #pragma unroll
          for (int r = 0; r < 4; r++)
            q[(lg * 4 + r) * 4] = f2us(acc[m][n][r] + bi[m][r]);
        }
    }
  } else {
    #pragma unroll
    for (int m = 0; m < 4; m++)
      #pragma unroll
      for (int r = 0; r < 4; r++) {
        const int o = o0 + wr * 64 + m * 16 + lg * 4 + r;
        const float bv = bias[o];
        const size_t rowbase = ((size_t)bz * O + o) * TTT + t0 + wc * 64 + lr;
        #pragma unroll
        for (int n = 0; n < 4; n++) {
          const size_t idx = rowbase + n * 16;
          of[idx] = acc[m][n][r] + bv + resid[idx];
        }
      }
  }
}

// ---------------- split-s all-register flash attention ----------------
// 4 waves/block: (qw = query 16-group, sh = s-half). Each wave: 16 queries x
// 512 s (8 tiles) fully in registers (permuted-row QK, in-reg P). Halves
// merged via LDS (m, l, 16 O-partials per lane). 8192 waves -> 32 waves/CU.
__global__ __launch_bounds__(256, 8) void attn_p(
    const unsigned short* __restrict__ qP,
    const unsigned short* __restrict__ kP,
    const unsigned short* __restrict__ vP,
    unsigned short* __restrict__ avP)
{
  const int bid = blockIdx.x;                        // 0..2047
  const int bh = ((bid >> 3) & 7) * 8 + (bid & 7);   // bh's 32 blocks share XCD
  const int tq = bid >> 6;                           // 0..31 (32-query chunk)
  const int b = bh >> 3, hh = bh & 7;
  const int tid = threadIdx.x;
  const int lane = tid & 63, w = tid >> 6;           // 4 waves
  const int qw = w & 1, sh = w >> 1;                 // query-sub, s-half
  const int lg = lane >> 4, lr = lane & 15;
  const int laneoff = (lg >> 1) * 256 + (lg & 1) * 128 + lr * 4;

  __shared__ float mrg[2][64][21];                   // [qw][lane][m,l,o0..15]

  const unsigned short* Qb = qP + ((size_t)bh << 16) + laneoff;
  const unsigned short* Kb = kP + ((size_t)bh << 16);      // laneoff in koff
  const unsigned short* Vb = vP + ((size_t)bh << 16) + laneoff;

  // permuted-row K frag offsets (shorts) per sn
  int koff[4];
  #pragma unroll
  for (int sn = 0; sn < 4; sn++) {
    const int s_local = (sn >> 1) * 32 + (sn & 1) * 4 + ((lr >> 2) << 3) + (lr & 3);
    koff[sn] = (s_local >> 4) * 1024 + (s_local & 15) * 4
             + (lg >> 1) * 256 + (lg & 1) * 128;
  }

  const int rt = tq * 2 + qw;                        // query subtile 0..63

  // Q B-frag (col=t=lr, k=c)
  bf16x8 aq[2];
  {
    const unsigned short* qa = Qb + rt * 1024;
    aq[0] = cat8(*reinterpret_cast<const s16x4*>(qa),
                 *reinterpret_cast<const s16x4*>(qa + 64));
    aq[1] = cat8(*reinterpret_cast<const s16x4*>(qa + 512),
                 *reinterpret_cast<const s16x4*>(qa + 512 + 64));
  }

  f32x4 opv[4];
  #pragma unroll
  for (int cn = 0; cn < 4; cn++) opv[cn] = f32x4{0.f, 0.f, 0.f, 0.f};
  float mrow = -1e30f, lrow = 0.f;
  const float SC2 = 0.125f * 1.44269504f;

  bf16x8 kf[4][2];
  f32x4 sc[4];

#define LOADK(tile) do {                                                   \
    const unsigned short* tb_ = Kb + (tile) * 4096;                        \
    _Pragma("unroll") for (int sn_ = 0; sn_ < 4; sn_++)                    \
      _Pragma("unroll") for (int k2_ = 0; k2_ < 2; k2_++) {                \
        const unsigned short* p_ = tb_ + koff[sn_] + k2_ * 512;            \
        kf[sn_][k2_] = cat8(*reinterpret_cast<const s16x4*>(p_),           \
                            *reinterpret_cast<const s16x4*>(p_ + 64));     \
      } } while (0)

#define QKT do {                                                           \
    __builtin_amdgcn_s_setprio(1);                                         \
    _Pragma("unroll") for (int sn_ = 0; sn_ < 4; sn_++) {                  \
      f32x4 t_ = __builtin_amdgcn_mfma_f32_16x16x32_bf16(                  \
          kf[sn_][0], aq[0], f32x4{0.f, 0.f, 0.f, 0.f}, 0, 0, 0);          \
      sc[sn_] = __builtin_amdgcn_mfma_f32_16x16x32_bf16(                   \
          kf[sn_][1], aq[1], t_, 0, 0, 0);                                 \
    }                                                                      \
    __builtin_amdgcn_s_setprio(0); } while (0)

  const int s0 = sh * 8;                             // this half's first tile
  LOADK(s0);
  QKT;
  LOADK(s0 + 1);

  for (int j = 0; j < 8; j++) {
    const int T = s0 + j;

    // V frags for this tile (A-operand: row=c, k=s) — issue loads early
    bf16x8 bv[4][2];
    #pragma unroll
    for (int cn = 0; cn < 4; cn++)
      #pragma unroll
      for (int k2 = 0; k2 < 2; k2++) {
        const unsigned short* p = Vb + (cn * 64 + T * 4 + k2 * 2) * 256;
        bv[cn][k2] = cat8(*reinterpret_cast<const s16x4*>(p),
                          *reinterpret_cast<const s16x4*>(p + 64));
      }

    // ---- lane-local softmax (query t = 16*rt + lr) ----
    float mx = fmaxf(fmaxf(hmax4(sc[0]), hmax4(sc[1])),
                     fmaxf(hmax4(sc[2]), hmax4(sc[3]))) * SC2;
    mx = fmaxf(mx, __shfl_xor(mx, 16));
    mx = fmaxf(mx, __shfl_xor(mx, 32));
    if (!__all(mx <= mrow + 8.f)) {                  // defer-max (log2 units)
      const float mn = fmaxf(mrow, mx);
      const float rsc = exp2f(mrow - mn);
      mrow = mn;
      lrow *= rsc;
      #pragma unroll
      for (int cn = 0; cn < 4; cn++)
        #pragma unroll
        for (int r = 0; r < 4; r++) opv[cn][r] *= rsc;
    }

    float e[4][4];
    float rs = 0.f;
    #pragma unroll
    for (int sn = 0; sn < 4; sn++) {
      #pragma unroll
      for (int r = 0; r < 4; r++)
        e[sn][r] = exp2f(fmaf(sc[sn][r], SC2, -mrow));
      rs += (e[sn][0] + e[sn][1]) + (e[sn][2] + e[sn][3]);
    }
    lrow += rs;

    // pack P B-frags fully in registers (s-order via K row perm)
    union U8 { unsigned int u[4]; bf16x8 v; };
    U8 a0, a1;
    a0.u[0] = pk2(e[0][0], e[0][1]); a0.u[1] = pk2(e[0][2], e[0][3]);
    a0.u[2] = pk2(e[1][0], e[1][1]); a0.u[3] = pk2(e[1][2], e[1][3]);
    a1.u[0] = pk2(e[2][0], e[2][1]); a1.u[1] = pk2(e[2][2], e[2][3]);
    a1.u[2] = pk2(e[3][0], e[3][1]); a1.u[3] = pk2(e[3][2], e[3][3]);
    const bf16x8 pb0 = a0.v, pb1 = a1.v;

    // next tile's QK (sc consumed) + K prefetch
    if (j < 7) {
      QKT;
      LOADK(s0 + (j + 2 < 8 ? j + 2 : 7));
    }

    // PV
    __builtin_amdgcn_s_setprio(1);
    #pragma unroll
    for (int cn = 0; cn < 4; cn++) {
      opv[cn] = __builtin_amdgcn_mfma_f32_16x16x32_bf16(bv[cn][0], pb0, opv[cn], 0, 0, 0);
      opv[cn] = __builtin_amdgcn_mfma_f32_16x16x32_bf16(bv[cn][1], pb1, opv[cn], 0, 0, 0);
    }
    __builtin_amdgcn_s_setprio(0);
  }

  // intra-wave l reduce (full sum over this half's 512 s)
  float lt = lrow;
  lt += __shfl_xor(lt, 16);
  lt += __shfl_xor(lt, 32);

  // ---- cross-half merge via LDS ----
  if (sh == 1) {
    mrg[qw][lane][0] = mrow;
    mrg[qw][lane][1] = lt;
    #pragma unroll
    for (int cn = 0; cn < 4; cn++)
      #pragma unroll
      for (int r = 0; r < 4; r++)
        mrg[qw][lane][2 + cn * 4 + r] = opv[cn][r];
  }
  __syncthreads();
  if (sh == 0) {
    const float m2 = mrg[qw][lane][0];
    const float l2 = mrg[qw][lane][1];
    const float mf = fmaxf(mrow, m2);
    const float s1 = exp2f(mrow - mf);
    const float s2 = exp2f(m2 - mf);
    const float linv = 1.f / (lt * s1 + l2 * s2);

    unsigned short* dst = avP + (size_t)b * 524288;
    #pragma unroll
    for (int cn = 0; cn < 4; cn++) {
      ushort4 o;
      o.x = f2us((opv[cn][0] * s1 + mrg[qw][lane][2 + cn * 4 + 0] * s2) * linv);
      o.y = f2us((opv[cn][1] * s1 + mrg[qw][lane][2 + cn * 4 + 1] * s2) * linv);
      o.z = f2us((opv[cn][2] * s1 + mrg[qw][lane][2 + cn * 4 + 2] * s2) * linv);
      o.w = f2us((opv[cn][3] * s1 + mrg[qw][lane][2 + cn * 4 + 3] * s2) * linv);
      *reinterpret_cast<ushort4*>(&dst[((size_t)(rt * 32 + hh * 4 + cn) << 8) + lg * 64 + lr * 4]) = o;
    }
  }
#undef LOADK
#undef QKT
}

extern "C" void kernel_launch(void* const* d_in, const int* in_sizes, int n_in,
                              void* d_out, int out_size, void* d_ws, size_t ws_size,
                              hipStream_t stream) {
  const float* x      = (const float*)d_in[0];
  const float* gn_w   = (const float*)d_in[1];
  const float* gn_b   = (const float*)d_in[2];
  const float* qkv_w  = (const float*)d_in[3];
  const float* qkv_b  = (const float*)d_in[4];
  const float* proj_w = (const float*)d_in[5];
  const float* proj_b = (const float*)d_in[6];
  float* out = (float*)d_out;

  const size_t HT = (size_t)BBB * TTT * CCH;
  const size_t QK = (size_t)BBB * NHEAD * TTT * CHD;
  unsigned short* hP  = (unsigned short*)d_ws;
  unsigned short* vP  = hP + HT;
  unsigned short* avP = vP + QK;
  unsigned short* wq  = avP + HT;
  unsigned short* wp  = wq + (size_t)O_QKV * CCH;
  unsigned short* qPd = (unsigned short*)d_out;   // scratch in d_out (rewritten)
  unsigned short* kPd = qPd + QK;

  const int nslot = (O_QKV + CCH) * CCH / 4;
  wpack_kernel<<<dim3(nslot / 256), 256, 0, stream>>>(qkv_w, proj_w, wq, nslot);
  gn_kernel<<<dim3(BBB * NGRP), 256, 0, stream>>>(x, gn_w, gn_b, hP);
  gemm_p<0><<<dim3(TTT / 128, O_QKV / 128, BBB), 256, 0, stream>>>(
      wq, hP, qkv_b, nullptr, qPd, kPd, vP, nullptr, O_QKV);
  attn_p<<<dim3(2048), 256, 0, stream>>>(qPd, kPd, vP, avP);
  gemm_p<1><<<dim3(TTT / 128, CCH / 128, BBB), 256, 0, stream>>>(
      wp, avP, proj_b, x, nullptr, nullptr, nullptr, out, CCH);
}

// Round 11
// 169.489 us; speedup vs baseline: 2.8917x; 2.8917x over previous
//
#include <hip/hip_runtime.h>
#include <hip/hip_bf16.h>

#define CCH 512
#define TTT 1024
#define BBB 8
#define NGRP 32
#define CPG 16
#define NHEAD 8
#define CHD 64
#define O_QKV 1536

typedef __attribute__((ext_vector_type(8))) short bf16x8;
typedef __attribute__((ext_vector_type(4))) short s16x4;
typedef __attribute__((ext_vector_type(4))) float f32x4;

__device__ __forceinline__ float us2f(unsigned short u) {
  union { unsigned int i; float f; } p; p.i = ((unsigned int)u) << 16; return p.f;
}
__device__ __forceinline__ unsigned short f2us(float f) {
  __hip_bfloat16 b = __float2bfloat16(f);
  return *reinterpret_cast<unsigned short*>(&b);
}
__device__ __forceinline__ bf16x8 cat8(s16x4 a, s16x4 b) {
  bf16x8 r;
  r[0] = a[0]; r[1] = a[1]; r[2] = a[2]; r[3] = a[3];
  r[4] = b[0]; r[5] = b[1]; r[6] = b[2]; r[7] = b[3];
  return r;
}
__device__ __forceinline__ float hmax4(f32x4 v) {
  return fmaxf(fmaxf(v[0], v[1]), fmaxf(v[2], v[3]));
}
__device__ __forceinline__ unsigned int pk2(float lo, float hi) {
  return ((unsigned int)f2us(hi) << 16) | (unsigned int)f2us(lo);
}

// Packed layout for a logical [R rows][K cols] bf16 matrix consumed as MFMA frags:
//   subtile (rt=row/16, kt=k/16) base = (rt*(K/16)+kt)*256
//   within: ((k%16)/4)*64 + (row%16)*4 + (k%4)

// ---------------- W f32 -> packed bf16 (qkv_w then proj_w, one launch) ----------------
__global__ __launch_bounds__(256) void wpack_kernel(
    const float* __restrict__ wq, const float* __restrict__ wp,
    unsigned short* __restrict__ op, int nslot)
{
  const int s = blockIdx.x * 256 + threadIdx.x;   // one ushort4 slot
  if (s >= nslot) return;
  const int u = s & 63, sub = s >> 6;
  const int kt = sub & 31, rt = sub >> 5;         // K = 512 -> 32 kt
  const int lg = u >> 4, lr = u & 15;
  const int row = rt * 16 + lr;
  const float* src = (row < O_QKV) ? &wq[(size_t)row * CCH]
                                   : &wp[(size_t)(row - O_QKV) * CCH];
  float4 v = *reinterpret_cast<const float4*>(&src[kt * 16 + lg * 4]);
  ushort4 r;
  r.x = f2us(v.x); r.y = f2us(v.y); r.z = f2us(v.z); r.w = f2us(v.w);
  reinterpret_cast<ushort4*>(op)[s] = r;
}

// ---------------- GroupNorm: f32 [b][c][t] -> packed H (row=t, k=c) ----------------
__global__ __launch_bounds__(256) void gn_kernel(
    const float* __restrict__ x,
    const float* __restrict__ gw,
    const float* __restrict__ gb,
    unsigned short* __restrict__ hP)
{
  __shared__ __align__(16) float xs[16][1028];
  const int bg = blockIdx.x;
  const int bb = bg >> 5, g = bg & 31;
  const size_t base = ((size_t)bb * CCH + (size_t)g * CPG) * TTT;
  const float4* xv = reinterpret_cast<const float4*>(x + base);
  const int tid = threadIdx.x;

  float s = 0.f, q = 0.f;
  for (int i = tid; i < 4096; i += 256) {
    float4 u = xv[i];
    const int c = i >> 8, t4 = (i & 255) << 2;
    *reinterpret_cast<float4*>(&xs[c][t4]) = u;
    s += (u.x + u.y) + (u.z + u.w);
    q += u.x * u.x + u.y * u.y + u.z * u.z + u.w * u.w;
  }
  #pragma unroll
  for (int off = 32; off > 0; off >>= 1) {
    s += __shfl_down(s, off);
    q += __shfl_down(q, off);
  }
  __shared__ float red[10];
  const int wid = tid >> 6, lane = tid & 63;
  if (lane == 0) { red[wid] = s; red[4 + wid] = q; }
  __syncthreads();
  if (tid == 0) {
    float S = red[0] + red[1] + red[2] + red[3];
    float Q = red[4] + red[5] + red[6] + red[7];
    float mu = S * (1.f / 16384.f);
    float var = Q * (1.f / 16384.f) - mu * mu;
    red[8] = mu;
    red[9] = rsqrtf(var + 1e-5f);
  }
  __syncthreads();
  const float mu = red[8], rstd = red[9];
  float wsc[16], wbs[16];
  #pragma unroll
  for (int cc = 0; cc < 16; cc++) {
    wsc[cc] = gw[g * CPG + cc] * rstd;
    wbs[cc] = gb[g * CPG + cc] - mu * wsc[cc];
  }
  for (int tt = tid; tt < 1024; tt += 256) {
    float v[16];
    #pragma unroll
    for (int cc = 0; cc < 16; cc++)
      v[cc] = fmaf(xs[cc][tt], wsc[cc], wbs[cc]);
    unsigned short* dst = &hP[(size_t)bb * 524288 + ((size_t)((tt >> 4) * 32 + g)) * 256 + (tt & 15) * 4];
    #pragma unroll
    for (int l2 = 0; l2 < 4; l2++) {
      ushort4 st;
      st.x = f2us(v[l2 * 4 + 0]);
      st.y = f2us(v[l2 * 4 + 1]);
      st.z = f2us(v[l2 * 4 + 2]);
      st.w = f2us(v[l2 * 4 + 3]);
      *reinterpret_cast<ushort4*>(&dst[l2 * 64]) = st;
    }
  }
}

// ---------------- LDS-free packed MFMA GEMM (unchanged) ----------------
template<int MODE>
__global__ __launch_bounds__(256) void gemm_p(
    const unsigned short* __restrict__ Ap,
    const unsigned short* __restrict__ Bp,
    const float* __restrict__ bias,
    const float* __restrict__ resid,
    unsigned short* __restrict__ oq,
    unsigned short* __restrict__ ok,
    unsigned short* __restrict__ ov,
    float* __restrict__ of,
    const int O)
{
  const int tid = threadIdx.x;
  const int bz = blockIdx.z, o0 = blockIdx.y << 7, t0 = blockIdx.x << 7;
  const int lane = tid & 63, w = tid >> 6;
  const int lg = lane >> 4, lr = lane & 15;
  const int wr = w >> 1, wc = w & 1;
  const int laneoff = (lg >> 1) * 256 + (lg & 1) * 128 + lr * 4;

  const unsigned short* Ab = Ap + (size_t)(((o0 >> 4) + wr * 4) * 32) * 256 + laneoff;
  const unsigned short* Bb = Bp + (size_t)bz * 524288
      + (size_t)(((t0 >> 4) + wc * 4) * 32) * 256 + laneoff;

  f32x4 acc[4][4];
  #pragma unroll
  for (int m = 0; m < 4; m++)
    #pragma unroll
    for (int n = 0; n < 4; n++) acc[m][n] = f32x4{0.f, 0.f, 0.f, 0.f};

  #pragma unroll 2
  for (int kb = 0; kb < 32; kb += 2) {
    bf16x8 af[4], bf[4];
    #pragma unroll
    for (int m = 0; m < 4; m++) {
      const unsigned short* p = Ab + (m * 32 + kb) * 256;
      af[m] = cat8(*reinterpret_cast<const s16x4*>(p),
                   *reinterpret_cast<const s16x4*>(p + 64));
    }
    #pragma unroll
    for (int n = 0; n < 4; n++) {
      const unsigned short* p = Bb + (n * 32 + kb) * 256;
      bf[n] = cat8(*reinterpret_cast<const s16x4*>(p),
                   *reinterpret_cast<const s16x4*>(p + 64));
    }
    #pragma unroll
    for (int n = 0; n < 4; n++)
      #pragma unroll
      for (int m = 0; m < 4; m++)
        acc[m][n] = __builtin_amdgcn_mfma_f32_16x16x32_bf16(af[m], bf[n], acc[m][n], 0, 0, 0);
  }

  if (MODE == 0) {
    const int a = (o0 >> 6) + wr;
    float bi[4][4];
    #pragma unroll
    for (int m = 0; m < 4; m++)
      #pragma unroll
      for (int r = 0; r < 4; r++)
        bi[m][r] = bias[a * 64 + m * 16 + lg * 4 + r];
    const int head = a / 3, part = a - head * 3;
    const size_t bho = ((size_t)bz * NHEAD + head) << 16;
    if (part < 2) {
      unsigned short* dst = (part == 0 ? oq : ok) + bho;
      #pragma unroll
      for (int n = 0; n < 4; n++) {
        const int rt4 = ((t0 >> 4) + wc * 4 + n) * 4;
        #pragma unroll
        for (int m = 0; m < 4; m++) {
          ushort4 st;
          st.x = f2us(acc[m][n][0] + bi[m][0]);
          st.y = f2us(acc[m][n][1] + bi[m][1]);
          st.z = f2us(acc[m][n][2] + bi[m][2]);
          st.w = f2us(acc[m][n][3] + bi[m][3]);
          *reinterpret_cast<ushort4*>(&dst[((size_t)(rt4 + m) << 8) + lg * 64 + lr * 4]) = st;
        }
      }
    } else {
      unsigned short* dst = ov + bho;
      const int vsub = (lr >> 2) * 64 + (lr & 3);
      #pragma unroll
      for (int m = 0; m < 4; m++)
        #pragma unroll
        for (int n = 0; n < 4; n++) {
          const int kt = (t0 >> 4) + wc * 4 + n;
          unsigned short* q = &dst[((size_t)(m * 64 + kt) << 8) + vsub];
          #pragma unroll
          for (int r = 0; r < 4; r++)
            q[(lg * 4 + r) * 4] = f2us(acc[m][n][r] + bi[m][r]);
        }
    }
  } else {
    #pragma unroll
    for (int m = 0; m < 4; m++)
      #pragma unroll
      for (int r = 0; r < 4; r++) {
        const int o = o0 + wr * 64 + m * 16 + lg * 4 + r;
        const float bv = bias[o];
        const size_t rowbase = ((size_t)bz * O + o) * TTT + t0 + wc * 64 + lr;
        #pragma unroll
        for (int n = 0; n < 4; n++) {
          const size_t idx = rowbase + n * 16;
          of[idx] = acc[m][n][r] + bv + resid[idx];
        }
      }
  }
}

// ---------------- split-s all-register flash attention (R9 loop, 2x grid) ----
// 512-thread blocks, 8 waves: qw = w&3 (query 16-group), sh = w>>2 (s-half).
// Inner loop identical to R9 (compiled to 64 VGPR there); budget kept at 128
// via __launch_bounds__(512,4) -- NEVER force 8 (R10 spill lesson).
// Grid 1024 -> 8192 waves; if VGPR stays <=64, HW residency = 32 waves/CU.
__global__ __launch_bounds__(512, 4) void attn_p(
    const unsigned short* __restrict__ qP,
    const unsigned short* __restrict__ kP,
    const unsigned short* __restrict__ vP,
    unsigned short* __restrict__ avP)
{
  const int bid = blockIdx.x;                        // 0..1023
  const int bh = (bid & 7) * 8 + ((bid >> 3) & 7);   // bh's 16 blocks share XCD
  const int tq = bid >> 6;                           // 0..15 (64-query chunk)
  const int b = bh >> 3, hh = bh & 7;
  const int tid = threadIdx.x;
  const int lane = tid & 63, w = tid >> 6;           // 8 waves
  const int qw = w & 3, sh = w >> 2;                 // query-sub, s-half
  const int lg = lane >> 4, lr = lane & 15;
  const int laneoff = (lg >> 1) * 256 + (lg & 1) * 128 + lr * 4;

  __shared__ float mrg[4][64][21];                   // [qw][lane][m,l,o0..15]

  const unsigned short* Qb = qP + ((size_t)bh << 16) + laneoff;
  const unsigned short* Kb = kP + ((size_t)bh << 16);      // laneoff in koff
  const unsigned short* Vb = vP + ((size_t)bh << 16) + laneoff;

  // permuted-row K frag offsets (shorts) per sn
  int koff[4];
  #pragma unroll
  for (int sn = 0; sn < 4; sn++) {
    const int s_local = (sn >> 1) * 32 + (sn & 1) * 4 + ((lr >> 2) << 3) + (lr & 3);
    koff[sn] = (s_local >> 4) * 1024 + (s_local & 15) * 4
             + (lg >> 1) * 256 + (lg & 1) * 128;
  }

  const int rt = tq * 4 + qw;                        // query subtile 0..63

  // Q B-frag (col=t=lr, k=c)
  bf16x8 aq[2];
  {
    const unsigned short* qa = Qb + rt * 1024;
    aq[0] = cat8(*reinterpret_cast<const s16x4*>(qa),
                 *reinterpret_cast<const s16x4*>(qa + 64));
    aq[1] = cat8(*reinterpret_cast<const s16x4*>(qa + 512),
                 *reinterpret_cast<const s16x4*>(qa + 512 + 64));
  }

  f32x4 opv[4];
  #pragma unroll
  for (int cn = 0; cn < 4; cn++) opv[cn] = f32x4{0.f, 0.f, 0.f, 0.f};
  float mrow = -1e30f, lrow = 0.f;
  const float SC2 = 0.125f * 1.44269504f;

  bf16x8 kf[4][2];
  f32x4 sc[4];

#define LOADK(tile) do {                                                   \
    const unsigned short* tb_ = Kb + (tile) * 4096;                        \
    _Pragma("unroll") for (int sn_ = 0; sn_ < 4; sn_++)                    \
      _Pragma("unroll") for (int k2_ = 0; k2_ < 2; k2_++) {                \
        const unsigned short* p_ = tb_ + koff[sn_] + k2_ * 512;            \
        kf[sn_][k2_] = cat8(*reinterpret_cast<const s16x4*>(p_),           \
                            *reinterpret_cast<const s16x4*>(p_ + 64));     \
      } } while (0)

#define QKT do {                                                           \
    __builtin_amdgcn_s_setprio(1);                                         \
    _Pragma("unroll") for (int sn_ = 0; sn_ < 4; sn_++) {                  \
      f32x4 t_ = __builtin_amdgcn_mfma_f32_16x16x32_bf16(                  \
          kf[sn_][0], aq[0], f32x4{0.f, 0.f, 0.f, 0.f}, 0, 0, 0);          \
      sc[sn_] = __builtin_amdgcn_mfma_f32_16x16x32_bf16(                   \
          kf[sn_][1], aq[1], t_, 0, 0, 0);                                 \
    }                                                                      \
    __builtin_amdgcn_s_setprio(0); } while (0)

  const int s0 = sh * 8;                             // this half's first tile
  LOADK(s0);
  QKT;
  LOADK(s0 + 1);

  for (int j = 0; j < 8; j++) {
    const int T = s0 + j;

    // V frags for this tile (A-operand: row=c, k=s) — issue loads early
    bf16x8 bv[4][2];
    #pragma unroll
    for (int cn = 0; cn < 4; cn++)
      #pragma unroll
      for (int k2 = 0; k2 < 2; k2++) {
        const unsigned short* p = Vb + (cn * 64 + T * 4 + k2 * 2) * 256;
        bv[cn][k2] = cat8(*reinterpret_cast<const s16x4*>(p),
                          *reinterpret_cast<const s16x4*>(p + 64));
      }

    // ---- lane-local softmax (query t = 16*rt + lr) ----
    float mx = fmaxf(fmaxf(hmax4(sc[0]), hmax4(sc[1])),
                     fmaxf(hmax4(sc[2]), hmax4(sc[3]))) * SC2;
    mx = fmaxf(mx, __shfl_xor(mx, 16));
    mx = fmaxf(mx, __shfl_xor(mx, 32));
    if (!__all(mx <= mrow + 8.f)) {                  // defer-max (log2 units)
      const float mn = fmaxf(mrow, mx);
      const float rsc = exp2f(mrow - mn);
      mrow = mn;
      lrow *= rsc;
      #pragma unroll
      for (int cn = 0; cn < 4; cn++)
        #pragma unroll
        for (int r = 0; r < 4; r++) opv[cn][r] *= rsc;
    }

    float e[4][4];
    float rs = 0.f;
    #pragma unroll
    for (int sn = 0; sn < 4; sn++) {
      #pragma unroll
      for (int r = 0; r < 4; r++)
        e[sn][r] = exp2f(fmaf(sc[sn][r], SC2, -mrow));
      rs += (e[sn][0] + e[sn][1]) + (e[sn][2] + e[sn][3]);
    }
    lrow += rs;

    // pack P B-frags fully in registers (s-order via K row perm)
    union U8 { unsigned int u[4]; bf16x8 v; };
    U8 a0, a1;
    a0.u[0] = pk2(e[0][0], e[0][1]); a0.u[1] = pk2(e[0][2], e[0][3]);
    a0.u[2] = pk2(e[1][0], e[1][1]); a0.u[3] = pk2(e[1][2], e[1][3]);
    a1.u[0] = pk2(e[2][0], e[2][1]); a1.u[1] = pk2(e[2][2], e[2][3]);
    a1.u[2] = pk2(e[3][0], e[3][1]); a1.u[3] = pk2(e[3][2], e[3][3]);
    const bf16x8 pb0 = a0.v, pb1 = a1.v;

    // next tile's QK (sc consumed) + K prefetch
    if (j < 7) {
      QKT;
      LOADK(s0 + (j + 2 < 8 ? j + 2 : 7));
    }

    // PV
    __builtin_amdgcn_s_setprio(1);
    #pragma unroll
    for (int cn = 0; cn < 4; cn++) {
      opv[cn] = __builtin_amdgcn_mfma_f32_16x16x32_bf16(bv[cn][0], pb0, opv[cn], 0, 0, 0);
      opv[cn] = __builtin_amdgcn_mfma_f32_16x16x32_bf16(bv[cn][1], pb1, opv[cn], 0, 0, 0);
    }
    __builtin_amdgcn_s_setprio(0);
  }

  // intra-wave l reduce (full sum over this half's 512 s)
  float lt = lrow;
  lt += __shfl_xor(lt, 16);
  lt += __shfl_xor(lt, 32);

  // ---- cross-half merge via LDS (stride 21 floats -> bank-conflict-free) ----
  if (sh == 1) {
    mrg[qw][lane][0] = mrow;
    mrg[qw][lane][1] = lt;
    #pragma unroll
    for (int cn = 0; cn < 4; cn++)
      #pragma unroll
      for (int r = 0; r < 4; r++)
        mrg[qw][lane][2 + cn * 4 + r] = opv[cn][r];
  }
  __syncthreads();
  if (sh == 0) {
    const float m2 = mrg[qw][lane][0];
    const float l2 = mrg[qw][lane][1];
    const float mf = fmaxf(mrow, m2);
    const float s1 = exp2f(mrow - mf);
    const float s2 = exp2f(m2 - mf);
    const float linv = 1.f / (lt * s1 + l2 * s2);

    unsigned short* dst = avP + (size_t)b * 524288;
    #pragma unroll
    for (int cn = 0; cn < 4; cn++) {
      ushort4 o;
      o.x = f2us((opv[cn][0] * s1 + mrg[qw][lane][2 + cn * 4 + 0] * s2) * linv);
      o.y = f2us((opv[cn][1] * s1 + mrg[qw][lane][2 + cn * 4 + 1] * s2) * linv);
      o.z = f2us((opv[cn][2] * s1 + mrg[qw][lane][2 + cn * 4 + 2] * s2) * linv);
      o.w = f2us((opv[cn][3] * s1 + mrg[qw][lane][2 + cn * 4 + 3] * s2) * linv);
      *reinterpret_cast<ushort4*>(&dst[((size_t)(rt * 32 + hh * 4 + cn) << 8) + lg * 64 + lr * 4]) = o;
    }
  }
#undef LOADK
#undef QKT
}

extern "C" void kernel_launch(void* const* d_in, const int* in_sizes, int n_in,
                              void* d_out, int out_size, void* d_ws, size_t ws_size,
                              hipStream_t stream) {
  const float* x      = (const float*)d_in[0];
  const float* gn_w   = (const float*)d_in[1];
  const float* gn_b   = (const float*)d_in[2];
  const float* qkv_w  = (const float*)d_in[3];
  const float* qkv_b  = (const float*)d_in[4];
  const float* proj_w = (const float*)d_in[5];
  const float* proj_b = (const float*)d_in[6];
  float* out = (float*)d_out;

  const size_t HT = (size_t)BBB * TTT * CCH;
  const size_t QK = (size_t)BBB * NHEAD * TTT * CHD;
  unsigned short* hP  = (unsigned short*)d_ws;
  unsigned short* vP  = hP + HT;
  unsigned short* avP = vP + QK;
  unsigned short* wq  = avP + HT;
  unsigned short* wp  = wq + (size_t)O_QKV * CCH;
  unsigned short* qPd = (unsigned short*)d_out;   // scratch in d_out (rewritten)
  unsigned short* kPd = qPd + QK;

  const int nslot = (O_QKV + CCH) * CCH / 4;
  wpack_kernel<<<dim3(nslot / 256), 256, 0, stream>>>(qkv_w, proj_w, wq, nslot);
  gn_kernel<<<dim3(BBB * NGRP), 256, 0, stream>>>(x, gn_w, gn_b, hP);
  gemm_p<0><<<dim3(TTT / 128, O_QKV / 128, BBB), 256, 0, stream>>>(
      wq, hP, qkv_b, nullptr, qPd, kPd, vP, nullptr, O_QKV);
  attn_p<<<dim3(1024), 512, 0, stream>>>(qPd, kPd, vP, avP);
  gemm_p<1><<<dim3(TTT / 128, CCH / 128, BBB), 256, 0, stream>>>(
      wp, avP, proj_b, x, nullptr, nullptr, nullptr, out, CCH);
}

// Round 12
// 97.758 us; speedup vs baseline: 5.0135x; 1.7338x over previous
//
#include <hip/hip_runtime.h>
#include <hip/hip_bf16.h>

#define CCH 512
#define TTT 1024
#define BBB 8
#define NGRP 32
#define CPG 16
#define NHEAD 8
#define CHD 64
#define O_QKV 1536

typedef __attribute__((ext_vector_type(8))) short bf16x8;
typedef __attribute__((ext_vector_type(4))) short s16x4;
typedef __attribute__((ext_vector_type(8))) unsigned short u16x8;
typedef __attribute__((ext_vector_type(4))) float f32x4;

__device__ __forceinline__ float us2f(unsigned short u) {
  union { unsigned int i; float f; } p; p.i = ((unsigned int)u) << 16; return p.f;
}
__device__ __forceinline__ unsigned short f2us(float f) {
  __hip_bfloat16 b = __float2bfloat16(f);
  return *reinterpret_cast<unsigned short*>(&b);
}
__device__ __forceinline__ bf16x8 cat8(s16x4 a, s16x4 b) {
  bf16x8 r;
  r[0] = a[0]; r[1] = a[1]; r[2] = a[2]; r[3] = a[3];
  r[4] = b[0]; r[5] = b[1]; r[6] = b[2]; r[7] = b[3];
  return r;
}
__device__ __forceinline__ float hmax4(f32x4 v) {
  return fmaxf(fmaxf(v[0], v[1]), fmaxf(v[2], v[3]));
}
__device__ __forceinline__ unsigned int pk2(float lo, float hi) {
  return ((unsigned int)f2us(hi) << 16) | (unsigned int)f2us(lo);
}

// OLD packed layout (hP, W, avP — unchanged): subtile base (rt*(K/16)+kt)*256,
// within: ((k%16)/4)*64 + (row%16)*4 + (k%4).
// NEW PL2 layout (qP, kP, vP only): same subtile order, within row-major:
// (row%16)*16 + (k%16). Frag = ONE b128 at (kt0+(lg>>1))*256 + lr*16 + (lg&1)*8.

// ---------------- W f32 -> packed bf16 (old layout, unchanged) ----------------
__global__ __launch_bounds__(256) void wpack_kernel(
    const float* __restrict__ wq, const float* __restrict__ wp,
    unsigned short* __restrict__ op, int nslot)
{
  const int s = blockIdx.x * 256 + threadIdx.x;
  if (s >= nslot) return;
  const int u = s & 63, sub = s >> 6;
  const int kt = sub & 31, rt = sub >> 5;
  const int lg = u >> 4, lr = u & 15;
  const int row = rt * 16 + lr;
  const float* src = (row < O_QKV) ? &wq[(size_t)row * CCH]
                                   : &wp[(size_t)(row - O_QKV) * CCH];
  float4 v = *reinterpret_cast<const float4*>(&src[kt * 16 + lg * 4]);
  ushort4 r;
  r.x = f2us(v.x); r.y = f2us(v.y); r.z = f2us(v.z); r.w = f2us(v.w);
  reinterpret_cast<ushort4*>(op)[s] = r;
}

// ---------------- GroupNorm (old hP layout, unchanged) ----------------
__global__ __launch_bounds__(256) void gn_kernel(
    const float* __restrict__ x,
    const float* __restrict__ gw,
    const float* __restrict__ gb,
    unsigned short* __restrict__ hP)
{
  __shared__ __align__(16) float xs[16][1028];
  const int bg = blockIdx.x;
  const int bb = bg >> 5, g = bg & 31;
  const size_t base = ((size_t)bb * CCH + (size_t)g * CPG) * TTT;
  const float4* xv = reinterpret_cast<const float4*>(x + base);
  const int tid = threadIdx.x;

  float s = 0.f, q = 0.f;
  for (int i = tid; i < 4096; i += 256) {
    float4 u = xv[i];
    const int c = i >> 8, t4 = (i & 255) << 2;
    *reinterpret_cast<float4*>(&xs[c][t4]) = u;
    s += (u.x + u.y) + (u.z + u.w);
    q += u.x * u.x + u.y * u.y + u.z * u.z + u.w * u.w;
  }
  #pragma unroll
  for (int off = 32; off > 0; off >>= 1) {
    s += __shfl_down(s, off);
    q += __shfl_down(q, off);
  }
  __shared__ float red[10];
  const int wid = tid >> 6, lane = tid & 63;
  if (lane == 0) { red[wid] = s; red[4 + wid] = q; }
  __syncthreads();
  if (tid == 0) {
    float S = red[0] + red[1] + red[2] + red[3];
    float Q = red[4] + red[5] + red[6] + red[7];
    float mu = S * (1.f / 16384.f);
    float var = Q * (1.f / 16384.f) - mu * mu;
    red[8] = mu;
    red[9] = rsqrtf(var + 1e-5f);
  }
  __syncthreads();
  const float mu = red[8], rstd = red[9];
  float wsc[16], wbs[16];
  #pragma unroll
  for (int cc = 0; cc < 16; cc++) {
    wsc[cc] = gw[g * CPG + cc] * rstd;
    wbs[cc] = gb[g * CPG + cc] - mu * wsc[cc];
  }
  for (int tt = tid; tt < 1024; tt += 256) {
    float v[16];
    #pragma unroll
    for (int cc = 0; cc < 16; cc++)
      v[cc] = fmaf(xs[cc][tt], wsc[cc], wbs[cc]);
    unsigned short* dst = &hP[(size_t)bb * 524288 + ((size_t)((tt >> 4) * 32 + g)) * 256 + (tt & 15) * 4];
    #pragma unroll
    for (int l2 = 0; l2 < 4; l2++) {
      ushort4 st;
      st.x = f2us(v[l2 * 4 + 0]);
      st.y = f2us(v[l2 * 4 + 1]);
      st.z = f2us(v[l2 * 4 + 2]);
      st.w = f2us(v[l2 * 4 + 3]);
      *reinterpret_cast<ushort4*>(&dst[l2 * 64]) = st;
    }
  }
}

// ---------------- LDS-free packed MFMA GEMM ----------------
// Loads (old layout) unchanged; MODE 0 epilogue now writes Q/K/V in PL2.
template<int MODE>
__global__ __launch_bounds__(256) void gemm_p(
    const unsigned short* __restrict__ Ap,
    const unsigned short* __restrict__ Bp,
    const float* __restrict__ bias,
    const float* __restrict__ resid,
    unsigned short* __restrict__ oq,
    unsigned short* __restrict__ ok,
    unsigned short* __restrict__ ov,
    float* __restrict__ of,
    const int O)
{
  const int tid = threadIdx.x;
  const int bz = blockIdx.z, o0 = blockIdx.y << 7, t0 = blockIdx.x << 7;
  const int lane = tid & 63, w = tid >> 6;
  const int lg = lane >> 4, lr = lane & 15;
  const int wr = w >> 1, wc = w & 1;
  const int laneoff = (lg >> 1) * 256 + (lg & 1) * 128 + lr * 4;

  const unsigned short* Ab = Ap + (size_t)(((o0 >> 4) + wr * 4) * 32) * 256 + laneoff;
  const unsigned short* Bb = Bp + (size_t)bz * 524288
      + (size_t)(((t0 >> 4) + wc * 4) * 32) * 256 + laneoff;

  f32x4 acc[4][4];
  #pragma unroll
  for (int m = 0; m < 4; m++)
    #pragma unroll
    for (int n = 0; n < 4; n++) acc[m][n] = f32x4{0.f, 0.f, 0.f, 0.f};

  #pragma unroll 2
  for (int kb = 0; kb < 32; kb += 2) {
    bf16x8 af[4], bf[4];
    #pragma unroll
    for (int m = 0; m < 4; m++) {
      const unsigned short* p = Ab + (m * 32 + kb) * 256;
      af[m] = cat8(*reinterpret_cast<const s16x4*>(p),
                   *reinterpret_cast<const s16x4*>(p + 64));
    }
    #pragma unroll
    for (int n = 0; n < 4; n++) {
      const unsigned short* p = Bb + (n * 32 + kb) * 256;
      bf[n] = cat8(*reinterpret_cast<const s16x4*>(p),
                   *reinterpret_cast<const s16x4*>(p + 64));
    }
    #pragma unroll
    for (int n = 0; n < 4; n++)
      #pragma unroll
      for (int m = 0; m < 4; m++)
        acc[m][n] = __builtin_amdgcn_mfma_f32_16x16x32_bf16(af[m], bf[n], acc[m][n], 0, 0, 0);
  }

  if (MODE == 0) {
    const int a = (o0 >> 6) + wr;
    float bi[4][4];
    #pragma unroll
    for (int m = 0; m < 4; m++)
      #pragma unroll
      for (int r = 0; r < 4; r++)
        bi[m][r] = bias[a * 64 + m * 16 + lg * 4 + r];
    const int head = a / 3, part = a - head * 3;
    const size_t bho = ((size_t)bz * NHEAD + head) << 16;
    if (part < 2) {
      // Q/K PL2 [1024 t][64 c]: subtile (rt=t/16, kt=m); off = lr*16 + lg*4
      unsigned short* dst = (part == 0 ? oq : ok) + bho;
      #pragma unroll
      for (int n = 0; n < 4; n++) {
        const int rt = (t0 >> 4) + wc * 4 + n;
        #pragma unroll
        for (int m = 0; m < 4; m++) {
          ushort4 st;
          st.x = f2us(acc[m][n][0] + bi[m][0]);
          st.y = f2us(acc[m][n][1] + bi[m][1]);
          st.z = f2us(acc[m][n][2] + bi[m][2]);
          st.w = f2us(acc[m][n][3] + bi[m][3]);
          *reinterpret_cast<ushort4*>(&dst[(size_t)(rt * 4 + m) * 256 + lr * 16 + lg * 4]) = st;
        }
      }
    } else {
      // V PL2 [64 c][1024 s]: subtile (rt=m, kt=s/16); off = (lg*4+r)*16 + lr
      unsigned short* dst = ov + bho;
      #pragma unroll
      for (int m = 0; m < 4; m++)
        #pragma unroll
        for (int n = 0; n < 4; n++) {
          const int kt = (t0 >> 4) + wc * 4 + n;
          unsigned short* q = &dst[(size_t)(m * 64 + kt) * 256 + lr];
          #pragma unroll
          for (int r = 0; r < 4; r++)
            q[(lg * 4 + r) * 16] = f2us(acc[m][n][r] + bi[m][r]);
        }
    }
  } else {
    #pragma unroll
    for (int m = 0; m < 4; m++)
      #pragma unroll
      for (int r = 0; r < 4; r++) {
        const int o = o0 + wr * 64 + m * 16 + lg * 4 + r;
        const float bv = bias[o];
        const size_t rowbase = ((size_t)bz * O + o) * TTT + t0 + wc * 64 + lr;
        #pragma unroll
        for (int n = 0; n < 4; n++) {
          const size_t idx = rowbase + n * 16;
          of[idx] = acc[m][n][r] + bv + resid[idx];
        }
      }
  }
}

// ---------------- LDS-staged flash attention ----------------
// 8 waves x 16 queries; K/V tiles (64 s) staged in LDS (PL2 + XOR swizzle:
// flip 16B-half iff row bit3), double-buffered, T14 split staging, 1 barrier
// per tile. QK^T = mfma(K_sigma_perm, Q) -> softmax lane-local, P in regs.
__global__ __launch_bounds__(512, 4) void attn_p(
    const unsigned short* __restrict__ qP,
    const unsigned short* __restrict__ kP,
    const unsigned short* __restrict__ vP,
    unsigned short* __restrict__ avP)
{
  const int bid = blockIdx.x;                    // 0..511
  const int bh = (bid & 7) * 8 + (bid >> 6);     // XCD-bijective (R9-proven)
  const int t0 = ((bid >> 3) & 7) << 7;          // 128-query block
  const int b = bh >> 3, hh = bh & 7;
  const int tid = threadIdx.x;
  const int lane = tid & 63, w = tid >> 6;       // 8 waves
  const int lg = lane >> 4, lr = lane & 15;

  __shared__ __align__(16) unsigned short kv[2][2][4096];  // [buf][K/V] 32 KB

  const unsigned short* Qb = qP + ((size_t)bh << 16);
  const unsigned short* Kb = kP + ((size_t)bh << 16);
  const unsigned short* Vb = vP + ((size_t)bh << 16);

  // ---- staging: thread = one 16B unit of K and one of V per tile ----
  const int p = tid;                             // unit 0..511
  const int swp8 = (p ^ ((p >> 4) & 1)) * 8;     // swizzled LDS short-offset
  const int vsrc0 = ((p >> 7) * 64 + ((p >> 5) & 3)) * 256 + (p & 31) * 8;  // + T*1024

  // ---- frag read offsets ----
  const int PLOFF = (lg >> 1) * 256 + lr * 16 + (lg & 1) * 8;      // PL2 global (shorts)
  const int hK = (lg & 1) ^ ((lr >> 2) & 1);
  const int hV = (lg & 1) ^ ((lr >> 3) & 1);
  int koff[4];                                   // LDS short-offsets (k2=0)
  #pragma unroll
  for (int sn = 0; sn < 4; sn++) {
    const int sub = ((sn >> 1) * 2 + (lr >> 3)) * 4 + (lg >> 1);
    const int row16 = (sn & 1) * 4 + ((lr >> 2) & 1) * 8 + (lr & 3);
    koff[sn] = sub * 256 + row16 * 16 + hK * 8;
  }
  const int voffb = (lg >> 1) * 256 + lr * 16 + hV * 8;

  // ---- Q frags (PL2 global, one b128 each) ----
  const int rt = (t0 >> 4) + w;
  const bf16x8 aq0 = *reinterpret_cast<const bf16x8*>(&Qb[rt * 1024 + PLOFF]);
  const bf16x8 aq1 = *reinterpret_cast<const bf16x8*>(&Qb[rt * 1024 + 512 + PLOFF]);

  f32x4 opv[4];
  #pragma unroll
  for (int cn = 0; cn < 4; cn++) opv[cn] = f32x4{0.f, 0.f, 0.f, 0.f};
  float mrow = -1e30f, lrow = 0.f;
  const float SC2 = 0.125f * 1.44269504f;

  // ---- prologue: stage tile 0 to buf0; load tile 1 into regs ----
  u16x8 rK = *reinterpret_cast<const u16x8*>(&Kb[p * 8]);
  u16x8 rV = *reinterpret_cast<const u16x8*>(&Vb[vsrc0]);
  *reinterpret_cast<u16x8*>(&kv[0][0][swp8]) = rK;
  *reinterpret_cast<u16x8*>(&kv[0][1][swp8]) = rV;
  rK = *reinterpret_cast<const u16x8*>(&Kb[4096 + p * 8]);
  rV = *reinterpret_cast<const u16x8*>(&Vb[1024 + vsrc0]);

  for (int T = 0; T < 16; T++) {
    const int buf = T & 1;
    __syncthreads();
    // write tile T+1 (in regs) to other buffer
    if (T + 1 < 16) {
      *reinterpret_cast<u16x8*>(&kv[buf ^ 1][0][swp8]) = rK;
      *reinterpret_cast<u16x8*>(&kv[buf ^ 1][1][swp8]) = rV;
    }
    // issue global loads for tile T+2 (latency hides under compute)
    if (T + 2 < 16) {
      rK = *reinterpret_cast<const u16x8*>(&Kb[(T + 2) * 4096 + p * 8]);
      rV = *reinterpret_cast<const u16x8*>(&Vb[(T + 2) * 1024 + vsrc0]);
    }

    // ---- K frags (sigma-permuted rows) + QK^T ----
    bf16x8 kf[4][2];
    #pragma unroll
    for (int sn = 0; sn < 4; sn++) {
      kf[sn][0] = *reinterpret_cast<const bf16x8*>(&kv[buf][0][koff[sn]]);
      kf[sn][1] = *reinterpret_cast<const bf16x8*>(&kv[buf][0][koff[sn] + 512]);
    }
    f32x4 sc[4];
    __builtin_amdgcn_s_setprio(1);
    #pragma unroll
    for (int sn = 0; sn < 4; sn++) {
      f32x4 t = __builtin_amdgcn_mfma_f32_16x16x32_bf16(kf[sn][0], aq0, f32x4{0.f, 0.f, 0.f, 0.f}, 0, 0, 0);
      sc[sn] = __builtin_amdgcn_mfma_f32_16x16x32_bf16(kf[sn][1], aq1, t, 0, 0, 0);
    }
    __builtin_amdgcn_s_setprio(0);

    // ---- V frags ----
    bf16x8 bv[4][2];
    #pragma unroll
    for (int cn = 0; cn < 4; cn++) {
      bv[cn][0] = *reinterpret_cast<const bf16x8*>(&kv[buf][1][cn * 1024 + voffb]);
      bv[cn][1] = *reinterpret_cast<const bf16x8*>(&kv[buf][1][cn * 1024 + 512 + voffb]);
    }

    // ---- lane-local softmax ----
    float mx = fmaxf(fmaxf(hmax4(sc[0]), hmax4(sc[1])),
                     fmaxf(hmax4(sc[2]), hmax4(sc[3]))) * SC2;
    mx = fmaxf(mx, __shfl_xor(mx, 16));
    mx = fmaxf(mx, __shfl_xor(mx, 32));
    if (!__all(mx <= mrow + 8.f)) {              // defer-max (log2 units)
      const float mn = fmaxf(mrow, mx);
      const float rsc = exp2f(mrow - mn);
      mrow = mn;
      lrow *= rsc;
      #pragma unroll
      for (int cn = 0; cn < 4; cn++)
        #pragma unroll
        for (int r = 0; r < 4; r++) opv[cn][r] *= rsc;
    }

    float e[4][4];
    float rs = 0.f;
    #pragma unroll
    for (int sn = 0; sn < 4; sn++) {
      #pragma unroll
      for (int r = 0; r < 4; r++)
        e[sn][r] = exp2f(fmaf(sc[sn][r], SC2, -mrow));
      rs += (e[sn][0] + e[sn][1]) + (e[sn][2] + e[sn][3]);
    }
    lrow += rs;

    // ---- pack P in registers (s-order via sigma) + PV ----
    union U8 { unsigned int u[4]; bf16x8 v; };
    U8 a0, a1;
    a0.u[0] = pk2(e[0][0], e[0][1]); a0.u[1] = pk2(e[0][2], e[0][3]);
    a0.u[2] = pk2(e[1][0], e[1][1]); a0.u[3] = pk2(e[1][2], e[1][3]);
    a1.u[0] = pk2(e[2][0], e[2][1]); a1.u[1] = pk2(e[2][2], e[2][3]);
    a1.u[2] = pk2(e[3][0], e[3][1]); a1.u[3] = pk2(e[3][2], e[3][3]);

    __builtin_amdgcn_s_setprio(1);
    #pragma unroll
    for (int cn = 0; cn < 4; cn++) {
      opv[cn] = __builtin_amdgcn_mfma_f32_16x16x32_bf16(bv[cn][0], a0.v, opv[cn], 0, 0, 0);
      opv[cn] = __builtin_amdgcn_mfma_f32_16x16x32_bf16(bv[cn][1], a1.v, opv[cn], 0, 0, 0);
    }
    __builtin_amdgcn_s_setprio(0);
  }

  // final l reduce across lg groups
  float lt = lrow;
  lt += __shfl_xor(lt, 16);
  lt += __shfl_xor(lt, 32);
  const float linv = 1.f / lt;

  // avP write (OLD packed layout — gemm1 unchanged)
  unsigned short* dst = avP + (size_t)b * 524288;
  #pragma unroll
  for (int cn = 0; cn < 4; cn++) {
    ushort4 o;
    o.x = f2us(opv[cn][0] * linv);
    o.y = f2us(opv[cn][1] * linv);
    o.z = f2us(opv[cn][2] * linv);
    o.w = f2us(opv[cn][3] * linv);
    *reinterpret_cast<ushort4*>(&dst[((size_t)(rt * 32 + hh * 4 + cn) << 8) + lg * 64 + lr * 4]) = o;
  }
}

extern "C" void kernel_launch(void* const* d_in, const int* in_sizes, int n_in,
                              void* d_out, int out_size, void* d_ws, size_t ws_size,
                              hipStream_t stream) {
  const float* x      = (const float*)d_in[0];
  const float* gn_w   = (const float*)d_in[1];
  const float* gn_b   = (const float*)d_in[2];
  const float* qkv_w  = (const float*)d_in[3];
  const float* qkv_b  = (const float*)d_in[4];
  const float* proj_w = (const float*)d_in[5];
  const float* proj_b = (const float*)d_in[6];
  float* out = (float*)d_out;

  const size_t HT = (size_t)BBB * TTT * CCH;
  const size_t QK = (size_t)BBB * NHEAD * TTT * CHD;
  unsigned short* hP  = (unsigned short*)d_ws;
  unsigned short* vP  = hP + HT;
  unsigned short* avP = vP + QK;
  unsigned short* wq  = avP + HT;
  unsigned short* wp  = wq + (size_t)O_QKV * CCH;
  unsigned short* qPd = (unsigned short*)d_out;   // scratch in d_out (rewritten)
  unsigned short* kPd = qPd + QK;

  const int nslot = (O_QKV + CCH) * CCH / 4;
  wpack_kernel<<<dim3(nslot / 256), 256, 0, stream>>>(qkv_w, proj_w, wq, nslot);
  gn_kernel<<<dim3(BBB * NGRP), 256, 0, stream>>>(x, gn_w, gn_b, hP);
  gemm_p<0><<<dim3(TTT / 128, O_QKV / 128, BBB), 256, 0, stream>>>(
      wq, hP, qkv_b, nullptr, qPd, kPd, vP, nullptr, O_QKV);
  attn_p<<<dim3(512), 512, 0, stream>>>(qPd, kPd, vP, avP);
  gemm_p<1><<<dim3(TTT / 128, CCH / 128, BBB), 256, 0, stream>>>(
      wp, avP, proj_b, x, nullptr, nullptr, nullptr, out, CCH);
}